// Round 8
// baseline (245.598 us; speedup 1.0000x reference)
//
#include <hip/hip_runtime.h>

#define CIN   256
#define OC    256
#define K_TOT 2304             // 256*9
#define CCH   32               // channels per K-chunk
#define NCHK  8                // K chunks
#define KCH   288              // k-values per chunk (tap-major: k = tap*32 + c)
#define SSTR  296              // LDS row stride (bf16 elems), 16B-aligned, padded
#define DM    64               // px per block (deform + conv), M-tile

#define N_DW  (OC * K_TOT)     // deform weight elements (589824)
#define N_OW  (32 * K_TOT)     // padded offset weight elements (73728)
#define N_CVT (2 * N_DW + 2 * N_OW)          // 1327104
#define CVT_BLOCKS (N_CVT / 4 / 256)         // 1296

typedef short  bf16x8 __attribute__((ext_vector_type(8)));
typedef float  f32x4  __attribute__((ext_vector_type(4)));
typedef unsigned short ushort_t;

__device__ __forceinline__ ushort_t f2bf(float f) {
    unsigned u = __builtin_bit_cast(unsigned, f);
    u += 0x7fffu + ((u >> 16) & 1u);          // RNE
    return (ushort_t)(u >> 16);
}
__device__ __forceinline__ float bf2f(short s) {
    return __builtin_bit_cast(float, ((unsigned)(unsigned short)s) << 16);
}

// ---------------------------------------------------------------------------
// prep kernel: (a) weight fp32->bf16 cvt with tap-major K permutation
//   dst[oc][cc][tap][cl] = src[oc][cc*32+cl][tap]   (4 elems/thread)
// (b) input transpose NCHW fp32 -> HWC bf16.
// blockIdx.x < CVT_BLOCKS -> cvt; else transpose (320 blocks).
// NOTE: offset-weight rows oc>=18 are stored as EXACT ZEROS — conv_gemm_k
// uses the last padded row (wk_o + 31*K_TOT) as a zero-page for OOB taps.
// ---------------------------------------------------------------------------
__global__ __launch_bounds__(256) void prep_k(
    const float* __restrict__ tdw, const float* __restrict__ sdw,
    const float* __restrict__ tow, const float* __restrict__ sow,
    const float* __restrict__ kin, const float* __restrict__ sin_,
    ushort_t* __restrict__ wk_d, ushort_t* __restrict__ ws_d,
    ushort_t* __restrict__ wk_o, ushort_t* __restrict__ ws_o,
    ushort_t* __restrict__ xt_k, ushort_t* __restrict__ xt_s)
{
    __shared__ ushort_t tile[64][264];    // transpose staging

    if (blockIdx.x < CVT_BLOCKS) {
        const int i = (blockIdx.x * 256 + threadIdx.x) * 4;
        const float* src; ushort_t* dst; int j; bool offw = false;
        if (i < N_DW)                    { src = tdw; dst = wk_d; j = i; }
        else if (i < 2 * N_DW)           { src = sdw; dst = ws_d; j = i - N_DW; }
        else if (i < 2 * N_DW + N_OW)    { src = tow; dst = wk_o; j = i - 2 * N_DW; offw = true; }
        else                             { src = sow; dst = ws_o; j = i - 2 * N_DW - N_OW; offw = true; }
        const int oc = j / K_TOT;
        const int k  = j - oc * K_TOT;
        const int cc = k / KCH;
        const int r  = k - cc * KCH;     // r%4==0, so cl..cl+3 share one tap
        const int tap = r >> 5;
        const int cl  = r & 31;
        ushort4 o4 = {0, 0, 0, 0};
        if (!offw || oc < 18) {
            const float* sp = &src[((size_t)oc * CIN + cc * 32 + cl) * 9 + tap];
            o4.x = f2bf(sp[0]); o4.y = f2bf(sp[9]); o4.z = f2bf(sp[18]); o4.w = f2bf(sp[27]);
        }
        *(ushort4*)&dst[j] = o4;
        return;
    }

    // ---- transpose branch -------------------------------------------------
    const int bx2 = blockIdx.x - CVT_BLOCKS;     // 0..319
    int H, W, b, px0; const float* x; ushort_t* xt;
    if (bx2 < 64) {                       // kernel: 16 b * 4 tiles
        H = 16; W = 16; x = kin; xt = xt_k;
        b = bx2 >> 2; px0 = (bx2 & 3) * 64;
    } else {                              // search: 16 b * 16 tiles
        int t2 = bx2 - 64;
        H = 32; W = 32; x = sin_; xt = xt_s;
        b = t2 >> 4; px0 = (t2 & 15) * 64;
    }
    const int HW = H * W;
    const int t = threadIdx.x, lane = t & 63, wv = t >> 6;
    const float* xb = x + (size_t)b * CIN * HW;

    for (int it = 0; it < 16; ++it) {
        const int ch = wv * 64 + it * 4 + (lane >> 4);
        const int pq = (lane & 15) * 4;
        float4 v = *(const float4*)&xb[(size_t)ch * HW + px0 + pq];
        tile[pq + 0][ch] = f2bf(v.x);
        tile[pq + 1][ch] = f2bf(v.y);
        tile[pq + 2][ch] = f2bf(v.z);
        tile[pq + 3][ch] = f2bf(v.w);
    }
    __syncthreads();
    for (int it = 0; it < 8; ++it) {
        const int px = it * 8 + wv * 2 + (lane >> 5);
        const int cg = (lane & 31) * 8;
        bf16x8 v = *(const bf16x8*)&tile[px][cg];
        *(bf16x8*)&xt[((size_t)b * HW + px0 + px) * 256 + cg] = v;
    }
}

// ---------------------------------------------------------------------------
// Offset conv as bf16 MFMA GEMM from HWC. M=64 px/block, N=32(18), K=2304.
// Round-8 rewrite: 320 blocks x 512 thr = 8 INDEPENDENT waves (mt 0..3 x
// nt 0..1); each wave owns a 16px x 16oc tile over the FULL K. No LDS, no
// reduce, no __syncthreads. Key fix vs r3/r7: the old `if(ok) a = load`
// guarded A-loads (288/wave) forced exec-mask churn that serialized every
// load; now OOB taps read a ZERO-PAGE (the always-zero padded rows of wk_o,
// oc 18..31) through a precomputed per-tap pointer -> all loads are
// unconditional and pipeline deeply. XCD-bijective swizzle keeps B + xt
// slices in local-XCD L2 (matches deform's mapping).
// blockIdx.x < 64 -> kernel branch, else search (256).
// ---------------------------------------------------------------------------
__global__ __launch_bounds__(512) void conv_gemm_k(
    const ushort_t* __restrict__ xt_k, const ushort_t* __restrict__ kwgt,
    const float* __restrict__ kbias, float* __restrict__ kout,
    const ushort_t* __restrict__ xt_s, const ushort_t* __restrict__ swgt,
    const float* __restrict__ sbias, float* __restrict__ sout,
    const ushort_t* __restrict__ zp)
{
    int H, W, sh, b, px0;
    const ushort_t* xt; const ushort_t* wgt; const float* bias; float* out;
    if (blockIdx.x < 64) {                // kernel: 16 b * 4 tiles
        const int xcd = blockIdx.x & 7, i = blockIdx.x >> 3;   // i: 0..7
        H = 16; W = 16; sh = 4; xt = xt_k; wgt = kwgt; bias = kbias; out = kout;
        b = xcd + 8 * (i & 1); px0 = (i >> 1) * 64;
    } else {                              // search: 16 b * 16 tiles
        const int t2 = blockIdx.x - 64;                        // 0..255
        const int xcd = t2 & 7, i = t2 >> 3;                   // i: 0..31
        H = 32; W = 32; sh = 5; xt = xt_s; wgt = swgt; bias = sbias; out = sout;
        b = xcd + 8 * (i & 1); px0 = (i >> 1) * 64;
    }
    const int HW = H * W;
    const int t = threadIdx.x, lane = t & 63, wv = t >> 6;
    const int mt = wv >> 1;               // px 16-row group
    const int nt = wv & 1;                // oc 16-half
    const int l15 = lane & 15;
    const int cg8 = (lane >> 4) * 8;
    const ushort_t* xtb = xt + (size_t)b * HW * 256;

    // pixel coords for this wave's 16 rows (lane-varying)
    const int px = px0 + mt * 16 + l15;
    const int h  = px >> sh;
    const int wc = px & (W - 1);

    // per-tap base pointer: valid -> xt row (+cg8), invalid -> zero-page.
    // All subsequent loads are UNCONDITIONAL (pa[ks] + cc*32).
    const ushort_t* pa[9];
#pragma unroll
    for (int ks = 0; ks < 9; ++ks) {
        const int y  = h + ks / 3 - 1;
        const int xx = wc + ks % 3 - 1;
        const bool ok = ((unsigned)y < (unsigned)H) && ((unsigned)xx < (unsigned)W);
        pa[ks] = ok ? (xtb + (size_t)(((y << sh) + xx) * 256 + cg8)) : zp;
    }
    const ushort_t* wrow = wgt + (size_t)(nt * 16 + l15) * K_TOT + cg8;

    f32x4 acc = {};
#pragma unroll
    for (int cc = 0; cc < NCHK; ++cc) {
#pragma unroll
        for (int ks = 0; ks < 9; ++ks) {
            const bf16x8 a  = *(const bf16x8*)&pa[ks][cc * 32];
            const bf16x8 b0 = *(const bf16x8*)&wrow[(size_t)cc * KCH + ks * 32];
            acc = __builtin_amdgcn_mfma_f32_16x16x32_bf16(a, b0, acc, 0, 0, 0);
        }
    }

    const int oc = nt * 16 + l15;
    if (oc < 18) {
        const float bs = bias[oc];
        const int prow = (lane >> 4) * 4;
        float4 r = { acc.x + bs, acc.y + bs, acc.z + bs, acc.w + bs };
        *(float4*)(out + ((size_t)b * 18 + oc) * HW + px0 + mt * 16 + prow) = r;
    }
}

// ---------------------------------------------------------------------------
// Deformable conv, bf16 MFMA GEMM from HWC. M=64, N=256, K=2304 tap-major.
// 320 blocks x 512 thr (8 waves); wave = oc column [wv*32,+32), mt-loop x4.
// EXACT round-5 structure (best measured: 96.7 us, VGPR 60, no spill):
// depth-2 gather pipeline (cA/cB), 2-deep rolling B buffer, XCD-bijective
// swizzle, raw lgkm-only barriers, setprio around MFMA. Round-6's
// producer/consumer split regressed (compiler de-pipelines deeper register
// chains; role split halves each role's width) — do not revisit.
// ---------------------------------------------------------------------------
__device__ __forceinline__ void dcn_load4(
    bf16x8* c, const ushort_t* __restrict__ xtb, int4 id, int cb)
{
    c[0] = *(const bf16x8*)&xtb[(size_t)id.x * 256 + cb];
    c[1] = *(const bf16x8*)&xtb[(size_t)id.y * 256 + cb];
    c[2] = *(const bf16x8*)&xtb[(size_t)id.z * 256 + cb];
    c[3] = *(const bf16x8*)&xtb[(size_t)id.w * 256 + cb];
}
__device__ __forceinline__ void dcn_proc2(
    ushort_t* swb, int so, const bf16x8* c, float4 wt)
{
    bf16x8 r;
#pragma unroll
    for (int j = 0; j < 8; ++j) {
        const float v = wt.x * bf2f(c[0][j]) + wt.y * bf2f(c[1][j])
                      + wt.z * bf2f(c[2][j]) + wt.w * bf2f(c[3][j]);
        r[j] = (short)f2bf(v);
    }
    *(bf16x8*)&swb[so] = r;
}

__global__ __launch_bounds__(512, 4) void deform_gemm_k(
    const ushort_t* __restrict__ xt_k, const float* __restrict__ koffs,
    const ushort_t* __restrict__ kwgt, float* __restrict__ kout,
    const ushort_t* __restrict__ xt_s, const float* __restrict__ soffs,
    const ushort_t* __restrict__ swgt_, float* __restrict__ sout)
{
    __shared__ __align__(16) ushort_t smp[DM][SSTR];    // 37.9 KB (single buf)
    __shared__ __align__(16) int      sidx[DM][9][4];   // 9.2 KB
    __shared__ __align__(16) float    swt [DM][9][4];   // 9.2 KB

    int H, W, b, px0;
    const ushort_t* xt; const float* offs; const ushort_t* wgt; float* out;
    // XCD-aware bijective swizzle: xcd = bx&7 (HW round-robin), batch = xcd
    // + 8*(i&1) so each XCD serves batches {x, x+8} only.
    if (blockIdx.x < 64) {                // kernel: 16 b * 4 tiles
        const int xcd = blockIdx.x & 7, i = blockIdx.x >> 3;   // i: 0..7
        H = 16; W = 16; xt = xt_k; offs = koffs; wgt = kwgt; out = kout;
        b = xcd + 8 * (i & 1); px0 = (i >> 1) * 64;
    } else {                              // search: 16 b * 16 tiles
        const int t2 = blockIdx.x - 64;                        // 0..255
        const int xcd = t2 & 7, i = t2 >> 3;                   // i: 0..31
        H = 32; W = 32; xt = xt_s; offs = soffs; wgt = swgt_; out = sout;
        b = xcd + 8 * (i & 1); px0 = (i >> 1) * 64;
    }
    const int HW = H * W;
    const int t = threadIdx.x, lane = t & 63, wv = t >> 6;

    // ---- phase 0: bilinear params, 576 (px,tap) units over 512 threads ----
#pragma unroll
    for (int u = 0; u < 2; ++u) {
        const int s = t + u * 512;
        if (s < DM * 9) {
            const int p = s / 9, k = s - 9 * p;
            const int pix = px0 + p;
            const int h  = pix / W;
            const int wc = pix - h * W;
            const float* ob = offs + (size_t)b * 18 * HW;
            const float dy = ob[(2 * k    ) * HW + pix];
            const float dx = ob[(2 * k + 1) * HW + pix];
            const float sy = (float)(h  + k / 3 - 1) + dy;
            const float sx = (float)(wc + k % 3 - 1) + dx;
            const float y0f = floorf(sy), x0f = floorf(sx);
            const float ly = sy - y0f, lx = sx - x0f;
            const int y0 = (int)y0f, x0 = (int)x0f;
#pragma unroll
            for (int j = 0; j < 4; ++j) {
                const int yy = y0 + (j >> 1);
                const int xx = x0 + (j & 1);
                const bool ok = ((unsigned)yy < (unsigned)H) && ((unsigned)xx < (unsigned)W);
                sidx[p][k][j] = min(max(yy, 0), H - 1) * W + min(max(xx, 0), W - 1);
                const float wj = ((j >> 1) ? ly : 1.f - ly) * ((j & 1) ? lx : 1.f - lx);
                swt[p][k][j] = ok ? wj : 0.f;
            }
        }
    }
    __syncthreads();

    const ushort_t* xtb = xt + (size_t)b * HW * 256;
    const int l15 = lane & 15;
    const int cg8 = (lane >> 4) * 8;
    const int ocb = wv * 32;
    const bool live4 = (t < 256);         // 2304 - 4*512 = 256 fifth-units

    // gather-unit geometry: unit q handles s = t + q*512;
    // g = s>>2 = g0 + q*128 (param index px*9+tap), cg = t&3 (const).
    const int g0  = t >> 2;
    const int cgE = (t & 3) * 8;          // element offset within 32-ch chunk
    int uso[5];                           // smp write offsets (elems)
#pragma unroll
    for (int q = 0; q < 5; ++q) {
        const int g  = g0 + q * 128;
        const int px = g / 9, tap = g - 9 * px;
        uso[q] = px * SSTR + tap * 32 + (t & 3) * 8;
    }

    const ushort_t* wrow0 = wgt + (size_t)(ocb      + l15) * K_TOT + cg8;
    const ushort_t* wrow1 = wgt + (size_t)(ocb + 16 + l15) * K_TOT + cg8;
    ushort_t* smpb = &smp[0][0];
    const int4*   sidxF = (const int4*)  &sidx[0][0][0];
    const float4* swtF  = (const float4*)&swt [0][0][0];

    f32x4 acc[4][2] = {};

    for (int cc = 0; cc < NCHK; ++cc) {
        const int cb = cc * 32 + cgE;
        const size_t kg0 = (size_t)cc * KCH;

        // ---- gather phase: depth-2 rolling pipeline (cA/cB slots) ---------
        bf16x8 cA[4], cB[4];
        float4 wA, wB;
        bf16x8 bq[2][2];
        { const int4 id = sidxF[g0];       wA = swtF[g0];       dcn_load4(cA, xtb, id, cb); }
        { const int4 id = sidxF[g0 + 128]; wB = swtF[g0 + 128]; dcn_load4(cB, xtb, id, cb); }
        // B ks0 group: pre-barrier issue, in flight across the barrier
        bq[0][0] = *(const bf16x8*)&wrow0[kg0];
        bq[0][1] = *(const bf16x8*)&wrow1[kg0];

        dcn_proc2(smpb, uso[0], cA, wA);
        { const int4 id = sidxF[g0 + 256]; wA = swtF[g0 + 256]; dcn_load4(cA, xtb, id, cb); }
        dcn_proc2(smpb, uso[1], cB, wB);
        { const int4 id = sidxF[g0 + 384]; wB = swtF[g0 + 384]; dcn_load4(cB, xtb, id, cb); }
        dcn_proc2(smpb, uso[2], cA, wA);
        if (live4) { const int4 id = sidxF[g0 + 512]; wA = swtF[g0 + 512]; dcn_load4(cA, xtb, id, cb); }
        dcn_proc2(smpb, uso[3], cB, wB);
        if (live4) dcn_proc2(smpb, uso[4], cA, wA);

        // ---- barrier A: smp writes visible (lgkm only, vmem in flight) ----
        asm volatile("s_waitcnt lgkmcnt(0)" ::: "memory");
        __builtin_amdgcn_sched_barrier(0);
        __builtin_amdgcn_s_barrier();
        __builtin_amdgcn_sched_barrier(0);

        // ---- MFMA phase: rolling 2-deep B register buffer -----------------
        __builtin_amdgcn_s_setprio(1);
#pragma unroll
        for (int ks = 0; ks < 9; ++ks) {
            if (ks < 8) {
                bq[(ks + 1) & 1][0] = *(const bf16x8*)&wrow0[kg0 + (size_t)(ks + 1) * 32];
                bq[(ks + 1) & 1][1] = *(const bf16x8*)&wrow1[kg0 + (size_t)(ks + 1) * 32];
            }
            bf16x8 a[4];
#pragma unroll
            for (int mt = 0; mt < 4; ++mt)
                a[mt] = *(const bf16x8*)&smp[mt * 16 + l15][ks * 32 + cg8];
#pragma unroll
            for (int mt = 0; mt < 4; ++mt) {
                acc[mt][0] = __builtin_amdgcn_mfma_f32_16x16x32_bf16(a[mt], bq[ks & 1][0], acc[mt][0], 0, 0, 0);
                acc[mt][1] = __builtin_amdgcn_mfma_f32_16x16x32_bf16(a[mt], bq[ks & 1][1], acc[mt][1], 0, 0, 0);
            }
        }
        __builtin_amdgcn_s_setprio(0);

        // ---- barrier B: all smp reads consumed before next chunk's writes -
        if (cc < NCHK - 1) {
            __builtin_amdgcn_sched_barrier(0);
            __builtin_amdgcn_s_barrier();
            __builtin_amdgcn_sched_barrier(0);
        }
    }

    // ---- epilogue ---------------------------------------------------------
    const int prow = (lane >> 4) * 4;
#pragma unroll
    for (int mt = 0; mt < 4; ++mt) {
#pragma unroll
        for (int nt = 0; nt < 2; ++nt) {
            const int oc = ocb + nt * 16 + l15;
            float* op = out + ((size_t)b * OC + oc) * HW + px0 + mt * 16 + prow;
            *(float4*)op = *(float4*)&acc[mt][nt];
        }
    }
}

// ---------------------------------------------------------------------------
// Launcher. Inputs: kernel, search, Toffset_w, Toffset_b, Tdeform_w,
//                   Soffset_w, Soffset_b, Sdeform_w
// Outputs: kernel_out[16,256,16,16], search_out[16,256,32,32],
//          kernel_offset[16,18,16,16], search_offset[16,18,32,32]
// d_ws: 13.2 MB (bf16 weights 2.66 MB + HWC inputs 10.5 MB).
// ---------------------------------------------------------------------------
extern "C" void kernel_launch(void* const* d_in, const int* in_sizes, int n_in,
                              void* d_out, int out_size, void* d_ws, size_t ws_size,
                              hipStream_t stream) {
    const float* kin = (const float*)d_in[0];
    const float* sin_ = (const float*)d_in[1];
    const float* tow = (const float*)d_in[2];
    const float* tob = (const float*)d_in[3];
    const float* tdw = (const float*)d_in[4];
    const float* sow = (const float*)d_in[5];
    const float* sob = (const float*)d_in[6];
    const float* sdw = (const float*)d_in[7];

    float* out = (float*)d_out;
    float* out_k  = out;                                      // 16*256*16*16
    float* out_s  = out_k + (size_t)16 * 256 * 16 * 16;       // 16*256*32*32
    float* out_ko = out_s + (size_t)16 * 256 * 32 * 32;       // 16*18*16*16
    float* out_so = out_ko + (size_t)16 * 18 * 16 * 16;       // 16*18*32*32

    ushort_t* wk_d = (ushort_t*)d_ws;                 // [256][2304] tap-major
    ushort_t* ws_d = wk_d + N_DW;
    ushort_t* wk_o = ws_d + N_DW;                     // [32][2304] tap-major
    ushort_t* ws_o = wk_o + N_OW;
    ushort_t* xt_k = ws_o + N_OW;                     // [16][256][256] HWC bf16
    ushort_t* xt_s = xt_k + (size_t)16 * 256 * 256;   // [16][1024][256]
    // zero-page for conv OOB taps: padded offset-weight row 31 (oc>=18 rows
    // are written as exact zeros by prep_k's cvt branch).
    const ushort_t* zp = wk_o + (size_t)31 * K_TOT;

    prep_k<<<dim3(CVT_BLOCKS + 320), 256, 0, stream>>>(
        tdw, sdw, tow, sow, kin, sin_,
        wk_d, ws_d, wk_o, ws_o, xt_k, xt_s);

    conv_gemm_k<<<dim3(320), 512, 0, stream>>>(
        xt_k, wk_o, tob, out_ko, xt_s, ws_o, sob, out_so, zp);

    deform_gemm_k<<<dim3(320), 512, 0, stream>>>(
        xt_k, out_ko, wk_d, out_k, xt_s, out_so, ws_d, out_s);
}

// Round 9
// 207.967 us; speedup vs baseline: 1.1809x; 1.1809x over previous
//
#include <hip/hip_runtime.h>

#define CIN   256
#define OC    256
#define K_TOT 2304             // 256*9
#define CCH   32               // channels per K-chunk
#define NCHK  8                // K chunks
#define KCH   288              // k-values per chunk (tap-major: k = tap*32 + c)
#define SSTR  296              // LDS row stride (bf16 elems), 16B-aligned, padded
#define DM    64               // px per block (deform + conv), M-tile

#define N_DW  (OC * K_TOT)     // deform weight elements (589824)
#define N_OW  (32 * K_TOT)     // padded offset weight elements (73728)
#define N_CVT (2 * N_DW + 2 * N_OW)          // 1327104
#define CVT_BLOCKS (N_CVT / 4 / 256)         // 1296
#define XT_K_ELEMS ((size_t)16 * 256 * 256)      // 1048576
#define XT_S_ELEMS ((size_t)16 * 1024 * 256)     // 4194304

typedef short  bf16x8 __attribute__((ext_vector_type(8)));
typedef float  f32x4  __attribute__((ext_vector_type(4)));
typedef unsigned short ushort_t;

__device__ __forceinline__ ushort_t f2bf(float f) {
    unsigned u = __builtin_bit_cast(unsigned, f);
    u += 0x7fffu + ((u >> 16) & 1u);          // RNE
    return (ushort_t)(u >> 16);
}
__device__ __forceinline__ float bf2f(short s) {
    return __builtin_bit_cast(float, ((unsigned)(unsigned short)s) << 16);
}

// ---------------------------------------------------------------------------
// prep kernel: (a) weight fp32->bf16 cvt with tap-major K permutation
//   dst[oc][cc][tap][cl] = src[oc][cc*32+cl][tap]   (4 elems/thread)
// (b) input transpose NCHW fp32 -> HWC bf16.
// Also zeroes the 256-elem ZERO ROW appended after xt_s — conv_gemm_k reads
// it (via branchless offset) for out-of-bounds taps.
// blockIdx.x < CVT_BLOCKS -> cvt; else transpose (320 blocks).
// ---------------------------------------------------------------------------
__global__ __launch_bounds__(256) void prep_k(
    const float* __restrict__ tdw, const float* __restrict__ sdw,
    const float* __restrict__ tow, const float* __restrict__ sow,
    const float* __restrict__ kin, const float* __restrict__ sin_,
    ushort_t* __restrict__ wk_d, ushort_t* __restrict__ ws_d,
    ushort_t* __restrict__ wk_o, ushort_t* __restrict__ ws_o,
    ushort_t* __restrict__ xt_k, ushort_t* __restrict__ xt_s)
{
    __shared__ ushort_t tile[64][264];    // transpose staging

    if (blockIdx.x == 0 && threadIdx.x < 64) {   // zero row for conv OOB taps
        ushort4 z = {0, 0, 0, 0};
        *(ushort4*)&xt_s[XT_S_ELEMS + (size_t)threadIdx.x * 4] = z;
    }

    if (blockIdx.x < CVT_BLOCKS) {
        const int i = (blockIdx.x * 256 + threadIdx.x) * 4;
        const float* src; ushort_t* dst; int j; bool offw = false;
        if (i < N_DW)                    { src = tdw; dst = wk_d; j = i; }
        else if (i < 2 * N_DW)           { src = sdw; dst = ws_d; j = i - N_DW; }
        else if (i < 2 * N_DW + N_OW)    { src = tow; dst = wk_o; j = i - 2 * N_DW; offw = true; }
        else                             { src = sow; dst = ws_o; j = i - 2 * N_DW - N_OW; offw = true; }
        const int oc = j / K_TOT;
        const int k  = j - oc * K_TOT;
        const int cc = k / KCH;
        const int r  = k - cc * KCH;     // r%4==0, so cl..cl+3 share one tap
        const int tap = r >> 5;
        const int cl  = r & 31;
        ushort4 o4 = {0, 0, 0, 0};
        if (!offw || oc < 18) {
            const float* sp = &src[((size_t)oc * CIN + cc * 32 + cl) * 9 + tap];
            o4.x = f2bf(sp[0]); o4.y = f2bf(sp[9]); o4.z = f2bf(sp[18]); o4.w = f2bf(sp[27]);
        }
        *(ushort4*)&dst[j] = o4;
        return;
    }

    // ---- transpose branch -------------------------------------------------
    const int bx2 = blockIdx.x - CVT_BLOCKS;     // 0..319
    int H, W, b, px0; const float* x; ushort_t* xt;
    if (bx2 < 64) {                       // kernel: 16 b * 4 tiles
        H = 16; W = 16; x = kin; xt = xt_k;
        b = bx2 >> 2; px0 = (bx2 & 3) * 64;
    } else {                              // search: 16 b * 16 tiles
        int t2 = bx2 - 64;
        H = 32; W = 32; x = sin_; xt = xt_s;
        b = t2 >> 4; px0 = (t2 & 15) * 64;
    }
    const int HW = H * W;
    const int t = threadIdx.x, lane = t & 63, wv = t >> 6;
    const float* xb = x + (size_t)b * CIN * HW;

    for (int it = 0; it < 16; ++it) {
        const int ch = wv * 64 + it * 4 + (lane >> 4);
        const int pq = (lane & 15) * 4;
        float4 v = *(const float4*)&xb[(size_t)ch * HW + px0 + pq];
        tile[pq + 0][ch] = f2bf(v.x);
        tile[pq + 1][ch] = f2bf(v.y);
        tile[pq + 2][ch] = f2bf(v.z);
        tile[pq + 3][ch] = f2bf(v.w);
    }
    __syncthreads();
    for (int it = 0; it < 8; ++it) {
        const int px = it * 8 + wv * 2 + (lane >> 5);
        const int cg = (lane & 31) * 8;
        bf16x8 v = *(const bf16x8*)&tile[px][cg];
        *(bf16x8*)&xt[((size_t)b * HW + px0 + px) * 256 + cg] = v;
    }
}

// ---------------------------------------------------------------------------
// Offset conv as bf16 MFMA GEMM from HWC. M=64 px/block, N=32(18), K=2304.
// Round-9: 320 blocks x 512 thr = 8 waves, wave = ONE K-chunk (kh = wv).
// Cross-round algebra (r3 rest=110, r7 +15, r8 +38) showed conv is A-load
// ISSUE-count / latency bound at 5 waves/CU; this keeps total A-issues
// EXACTLY at r3's minimum (nt-inside: each A feeds 2 MFMAs; 320x8x36 =
// 320x4x72) while halving the per-wave serial chain and doubling occupancy
// (10 waves/CU). A-loads are unconditional (branchless zero-row offset,
// mechanism correctness-verified in r8) so they pipeline without exec-mask
// churn. K-partials combined via a 63 KB LDS reduce (one barrier).
// XCD-bijective swizzle matches deform's mapping.
// blockIdx.x < 64 -> kernel branch, else search (256).
// ---------------------------------------------------------------------------
__global__ __launch_bounds__(512, 2) void conv_gemm_k(
    const ushort_t* __restrict__ xt_k, const ushort_t* __restrict__ kwgt,
    const float* __restrict__ kbias, float* __restrict__ kout,
    const ushort_t* __restrict__ xt_s, const ushort_t* __restrict__ swgt,
    const float* __restrict__ sbias, float* __restrict__ sout)
{
    __shared__ float sred[7][64][36];     // 63 KB: [kh-1][lane][(mt*2+nt)*4]

    int H, W, sh, b, px0; int zrel;
    const ushort_t* xt; const ushort_t* wgt; const float* bias; float* out;
    if (blockIdx.x < 64) {                // kernel: 16 b * 4 tiles
        const int xcd = blockIdx.x & 7, i = blockIdx.x >> 3;   // i: 0..7
        H = 16; W = 16; sh = 4; xt = xt_k; wgt = kwgt; bias = kbias; out = kout;
        b = xcd + 8 * (i & 1); px0 = (i >> 1) * 64;
        zrel = (int)(XT_K_ELEMS + XT_S_ELEMS - (size_t)b * 256 * 256);
    } else {                              // search: 16 b * 16 tiles
        const int t2 = blockIdx.x - 64;                        // 0..255
        const int xcd = t2 & 7, i = t2 >> 3;                   // i: 0..31
        H = 32; W = 32; sh = 5; xt = xt_s; wgt = swgt; bias = sbias; out = sout;
        b = xcd + 8 * (i & 1); px0 = (i >> 1) * 64;
        zrel = (int)(XT_S_ELEMS - (size_t)b * 1024 * 256);
    }
    const int HW = H * W;
    const int t = threadIdx.x, lane = t & 63, kh = t >> 6;     // kh = chunk
    const int l15 = lane & 15;
    const int cg8 = (lane >> 4) * 8;
    const ushort_t* xtb = xt + (size_t)b * HW * 256;

    // per-mt pixel coords (lane-varying)
    int h[4], wc[4];
#pragma unroll
    for (int mt = 0; mt < 4; ++mt) {
        const int px = px0 + mt * 16 + l15;
        h[mt]  = px >> sh;
        wc[mt] = px & (W - 1);
    }
    const ushort_t* wrow0 = wgt + (size_t)(l15)      * K_TOT + cg8;
    const ushort_t* wrow1 = wgt + (size_t)(16 + l15) * K_TOT + cg8;
    const int cb = kh * 32 + cg8;
    const size_t kg0 = (size_t)kh * KCH;

    f32x4 acc[4][2] = {};
#pragma unroll
    for (int ks = 0; ks < 9; ++ks) {
        const bf16x8 b0 = *(const bf16x8*)&wrow0[kg0 + (size_t)ks * 32];
        const bf16x8 b1 = *(const bf16x8*)&wrow1[kg0 + (size_t)ks * 32];
        const int dy = ks / 3 - 1, dx = ks % 3 - 1;
        bf16x8 a[4];
#pragma unroll
        for (int mt = 0; mt < 4; ++mt) {
            const int y  = h[mt] + dy;
            const int xx = wc[mt] + dx;
            const bool ok = ((unsigned)y < (unsigned)H) && ((unsigned)xx < (unsigned)W);
            const int off = ok ? (((y << sh) + xx) * 256 + cb) : (zrel + cb);
            a[mt] = *(const bf16x8*)&xtb[off];      // unconditional
        }
#pragma unroll
        for (int mt = 0; mt < 4; ++mt) {
            acc[mt][0] = __builtin_amdgcn_mfma_f32_16x16x32_bf16(a[mt], b0, acc[mt][0], 0, 0, 0);
            acc[mt][1] = __builtin_amdgcn_mfma_f32_16x16x32_bf16(a[mt], b1, acc[mt][1], 0, 0, 0);
        }
    }

    if (kh > 0) {
#pragma unroll
        for (int mt = 0; mt < 4; ++mt)
#pragma unroll
            for (int nt = 0; nt < 2; ++nt)
                *(float4*)&sred[kh - 1][lane][(mt * 2 + nt) * 4] = *(float4*)&acc[mt][nt];
    }
    __syncthreads();
    if (kh == 0) {
        const int prow = (lane >> 4) * 4;
#pragma unroll
        for (int nt = 0; nt < 2; ++nt) {
            const int oc = nt * 16 + l15;
            if (oc < 18) {
                const float bs = bias[oc];
#pragma unroll
                for (int mt = 0; mt < 4; ++mt) {
                    float4 r = *(float4*)&acc[mt][nt];
#pragma unroll
                    for (int q = 0; q < 7; ++q) {
                        const float4 o = *(const float4*)&sred[q][lane][(mt * 2 + nt) * 4];
                        r.x += o.x; r.y += o.y; r.z += o.z; r.w += o.w;
                    }
                    r.x += bs; r.y += bs; r.z += bs; r.w += bs;
                    *(float4*)(out + ((size_t)b * 18 + oc) * HW + px0 + mt * 16 + prow) = r;
                }
            }
        }
    }
}

// ---------------------------------------------------------------------------
// Deformable conv, bf16 MFMA GEMM from HWC. M=64, N=256, K=2304 tap-major.
// 320 blocks x 512 thr (8 waves); wave = oc column [wv*32,+32), mt-loop x4.
// EXACT round-5 structure (best measured: 96.7-97.7 us across 3 runs, VGPR
// 60, no spill): depth-2 gather pipeline (cA/cB), 2-deep rolling B buffer,
// XCD-bijective swizzle, raw lgkm-only barriers, setprio around MFMA.
// ---------------------------------------------------------------------------
__device__ __forceinline__ void dcn_load4(
    bf16x8* c, const ushort_t* __restrict__ xtb, int4 id, int cb)
{
    c[0] = *(const bf16x8*)&xtb[(size_t)id.x * 256 + cb];
    c[1] = *(const bf16x8*)&xtb[(size_t)id.y * 256 + cb];
    c[2] = *(const bf16x8*)&xtb[(size_t)id.z * 256 + cb];
    c[3] = *(const bf16x8*)&xtb[(size_t)id.w * 256 + cb];
}
__device__ __forceinline__ void dcn_proc2(
    ushort_t* swb, int so, const bf16x8* c, float4 wt)
{
    bf16x8 r;
#pragma unroll
    for (int j = 0; j < 8; ++j) {
        const float v = wt.x * bf2f(c[0][j]) + wt.y * bf2f(c[1][j])
                      + wt.z * bf2f(c[2][j]) + wt.w * bf2f(c[3][j]);
        r[j] = (short)f2bf(v);
    }
    *(bf16x8*)&swb[so] = r;
}

__global__ __launch_bounds__(512, 4) void deform_gemm_k(
    const ushort_t* __restrict__ xt_k, const float* __restrict__ koffs,
    const ushort_t* __restrict__ kwgt, float* __restrict__ kout,
    const ushort_t* __restrict__ xt_s, const float* __restrict__ soffs,
    const ushort_t* __restrict__ swgt_, float* __restrict__ sout)
{
    __shared__ __align__(16) ushort_t smp[DM][SSTR];    // 37.9 KB (single buf)
    __shared__ __align__(16) int      sidx[DM][9][4];   // 9.2 KB
    __shared__ __align__(16) float    swt [DM][9][4];   // 9.2 KB

    int H, W, b, px0;
    const ushort_t* xt; const float* offs; const ushort_t* wgt; float* out;
    // XCD-aware bijective swizzle: xcd = bx&7 (HW round-robin), batch = xcd
    // + 8*(i&1) so each XCD serves batches {x, x+8} only.
    if (blockIdx.x < 64) {                // kernel: 16 b * 4 tiles
        const int xcd = blockIdx.x & 7, i = blockIdx.x >> 3;   // i: 0..7
        H = 16; W = 16; xt = xt_k; offs = koffs; wgt = kwgt; out = kout;
        b = xcd + 8 * (i & 1); px0 = (i >> 1) * 64;
    } else {                              // search: 16 b * 16 tiles
        const int t2 = blockIdx.x - 64;                        // 0..255
        const int xcd = t2 & 7, i = t2 >> 3;                   // i: 0..31
        H = 32; W = 32; xt = xt_s; offs = soffs; wgt = swgt_; out = sout;
        b = xcd + 8 * (i & 1); px0 = (i >> 1) * 64;
    }
    const int HW = H * W;
    const int t = threadIdx.x, lane = t & 63, wv = t >> 6;

    // ---- phase 0: bilinear params, 576 (px,tap) units over 512 threads ----
#pragma unroll
    for (int u = 0; u < 2; ++u) {
        const int s = t + u * 512;
        if (s < DM * 9) {
            const int p = s / 9, k = s - 9 * p;
            const int pix = px0 + p;
            const int h  = pix / W;
            const int wc = pix - h * W;
            const float* ob = offs + (size_t)b * 18 * HW;
            const float dy = ob[(2 * k    ) * HW + pix];
            const float dx = ob[(2 * k + 1) * HW + pix];
            const float sy = (float)(h  + k / 3 - 1) + dy;
            const float sx = (float)(wc + k % 3 - 1) + dx;
            const float y0f = floorf(sy), x0f = floorf(sx);
            const float ly = sy - y0f, lx = sx - x0f;
            const int y0 = (int)y0f, x0 = (int)x0f;
#pragma unroll
            for (int j = 0; j < 4; ++j) {
                const int yy = y0 + (j >> 1);
                const int xx = x0 + (j & 1);
                const bool ok = ((unsigned)yy < (unsigned)H) && ((unsigned)xx < (unsigned)W);
                sidx[p][k][j] = min(max(yy, 0), H - 1) * W + min(max(xx, 0), W - 1);
                const float wj = ((j >> 1) ? ly : 1.f - ly) * ((j & 1) ? lx : 1.f - lx);
                swt[p][k][j] = ok ? wj : 0.f;
            }
        }
    }
    __syncthreads();

    const ushort_t* xtb = xt + (size_t)b * HW * 256;
    const int l15 = lane & 15;
    const int cg8 = (lane >> 4) * 8;
    const int ocb = wv * 32;
    const bool live4 = (t < 256);         // 2304 - 4*512 = 256 fifth-units

    // gather-unit geometry: unit q handles s = t + q*512;
    // g = s>>2 = g0 + q*128 (param index px*9+tap), cg = t&3 (const).
    const int g0  = t >> 2;
    const int cgE = (t & 3) * 8;          // element offset within 32-ch chunk
    int uso[5];                           // smp write offsets (elems)
#pragma unroll
    for (int q = 0; q < 5; ++q) {
        const int g  = g0 + q * 128;
        const int px = g / 9, tap = g - 9 * px;
        uso[q] = px * SSTR + tap * 32 + (t & 3) * 8;
    }

    const ushort_t* wrow0 = wgt + (size_t)(ocb      + l15) * K_TOT + cg8;
    const ushort_t* wrow1 = wgt + (size_t)(ocb + 16 + l15) * K_TOT + cg8;
    ushort_t* smpb = &smp[0][0];
    const int4*   sidxF = (const int4*)  &sidx[0][0][0];
    const float4* swtF  = (const float4*)&swt [0][0][0];

    f32x4 acc[4][2] = {};

    for (int cc = 0; cc < NCHK; ++cc) {
        const int cb = cc * 32 + cgE;
        const size_t kg0 = (size_t)cc * KCH;

        // ---- gather phase: depth-2 rolling pipeline (cA/cB slots) ---------
        bf16x8 cA[4], cB[4];
        float4 wA, wB;
        bf16x8 bq[2][2];
        { const int4 id = sidxF[g0];       wA = swtF[g0];       dcn_load4(cA, xtb, id, cb); }
        { const int4 id = sidxF[g0 + 128]; wB = swtF[g0 + 128]; dcn_load4(cB, xtb, id, cb); }
        // B ks0 group: pre-barrier issue, in flight across the barrier
        bq[0][0] = *(const bf16x8*)&wrow0[kg0];
        bq[0][1] = *(const bf16x8*)&wrow1[kg0];

        dcn_proc2(smpb, uso[0], cA, wA);
        { const int4 id = sidxF[g0 + 256]; wA = swtF[g0 + 256]; dcn_load4(cA, xtb, id, cb); }
        dcn_proc2(smpb, uso[1], cB, wB);
        { const int4 id = sidxF[g0 + 384]; wB = swtF[g0 + 384]; dcn_load4(cB, xtb, id, cb); }
        dcn_proc2(smpb, uso[2], cA, wA);
        if (live4) { const int4 id = sidxF[g0 + 512]; wA = swtF[g0 + 512]; dcn_load4(cA, xtb, id, cb); }
        dcn_proc2(smpb, uso[3], cB, wB);
        if (live4) dcn_proc2(smpb, uso[4], cA, wA);

        // ---- barrier A: smp writes visible (lgkm only, vmem in flight) ----
        asm volatile("s_waitcnt lgkmcnt(0)" ::: "memory");
        __builtin_amdgcn_sched_barrier(0);
        __builtin_amdgcn_s_barrier();
        __builtin_amdgcn_sched_barrier(0);

        // ---- MFMA phase: rolling 2-deep B register buffer -----------------
        __builtin_amdgcn_s_setprio(1);
#pragma unroll
        for (int ks = 0; ks < 9; ++ks) {
            if (ks < 8) {
                bq[(ks + 1) & 1][0] = *(const bf16x8*)&wrow0[kg0 + (size_t)(ks + 1) * 32];
                bq[(ks + 1) & 1][1] = *(const bf16x8*)&wrow1[kg0 + (size_t)(ks + 1) * 32];
            }
            bf16x8 a[4];
#pragma unroll
            for (int mt = 0; mt < 4; ++mt)
                a[mt] = *(const bf16x8*)&smp[mt * 16 + l15][ks * 32 + cg8];
#pragma unroll
            for (int mt = 0; mt < 4; ++mt) {
                acc[mt][0] = __builtin_amdgcn_mfma_f32_16x16x32_bf16(a[mt], bq[ks & 1][0], acc[mt][0], 0, 0, 0);
                acc[mt][1] = __builtin_amdgcn_mfma_f32_16x16x32_bf16(a[mt], bq[ks & 1][1], acc[mt][1], 0, 0, 0);
            }
        }
        __builtin_amdgcn_s_setprio(0);

        // ---- barrier B: all smp reads consumed before next chunk's writes -
        if (cc < NCHK - 1) {
            __builtin_amdgcn_sched_barrier(0);
            __builtin_amdgcn_s_barrier();
            __builtin_amdgcn_sched_barrier(0);
        }
    }

    // ---- epilogue ---------------------------------------------------------
    const int prow = (lane >> 4) * 4;
#pragma unroll
    for (int mt = 0; mt < 4; ++mt) {
#pragma unroll
        for (int nt = 0; nt < 2; ++nt) {
            const int oc = ocb + nt * 16 + l15;
            float* op = out + ((size_t)b * OC + oc) * HW + px0 + mt * 16 + prow;
            *(float4*)op = *(float4*)&acc[mt][nt];
        }
    }
}

// ---------------------------------------------------------------------------
// Launcher. Inputs: kernel, search, Toffset_w, Toffset_b, Tdeform_w,
//                   Soffset_w, Soffset_b, Sdeform_w
// Outputs: kernel_out[16,256,16,16], search_out[16,256,32,32],
//          kernel_offset[16,18,16,16], search_offset[16,18,32,32]
// d_ws: 13.15 MB (bf16 weights 2.66 MB + HWC inputs 10.49 MB + 512 B zero
// row appended after xt_s for conv's OOB taps).
// ---------------------------------------------------------------------------
extern "C" void kernel_launch(void* const* d_in, const int* in_sizes, int n_in,
                              void* d_out, int out_size, void* d_ws, size_t ws_size,
                              hipStream_t stream) {
    const float* kin = (const float*)d_in[0];
    const float* sin_ = (const float*)d_in[1];
    const float* tow = (const float*)d_in[2];
    const float* tob = (const float*)d_in[3];
    const float* tdw = (const float*)d_in[4];
    const float* sow = (const float*)d_in[5];
    const float* sob = (const float*)d_in[6];
    const float* sdw = (const float*)d_in[7];

    float* out = (float*)d_out;
    float* out_k  = out;                                      // 16*256*16*16
    float* out_s  = out_k + (size_t)16 * 256 * 16 * 16;       // 16*256*32*32
    float* out_ko = out_s + (size_t)16 * 256 * 32 * 32;       // 16*18*16*16
    float* out_so = out_ko + (size_t)16 * 18 * 16 * 16;       // 16*18*32*32

    ushort_t* wk_d = (ushort_t*)d_ws;                 // [256][2304] tap-major
    ushort_t* ws_d = wk_d + N_DW;
    ushort_t* wk_o = ws_d + N_DW;                     // [32][2304] tap-major
    ushort_t* ws_o = wk_o + N_OW;
    ushort_t* xt_k = ws_o + N_OW;                     // [16][256][256] HWC bf16
    ushort_t* xt_s = xt_k + XT_K_ELEMS;               // [16][1024][256]
    // zero row (256 elems) lives at xt_s + XT_S_ELEMS; prep_k writes it.

    prep_k<<<dim3(CVT_BLOCKS + 320), 256, 0, stream>>>(
        tdw, sdw, tow, sow, kin, sin_,
        wk_d, ws_d, wk_o, ws_o, xt_k, xt_s);

    conv_gemm_k<<<dim3(320), 512, 0, stream>>>(
        xt_k, wk_o, tob, out_ko, xt_s, ws_o, sob, out_so);

    deform_gemm_k<<<dim3(320), 512, 0, stream>>>(
        xt_k, out_ko, wk_d, out_k, xt_s, out_so, ws_d, out_s);
}

// Round 10
// 205.646 us; speedup vs baseline: 1.1943x; 1.0113x over previous
//
#include <hip/hip_runtime.h>

#define CIN   256
#define OC    256
#define K_TOT 2304             // 256*9
#define CCH   32               // channels per K-chunk
#define NCHK  8                // K chunks
#define KCH   288              // k-values per chunk (tap-major: k = tap*32 + c)
#define SSTR  296              // LDS row stride (bf16 elems), 16B-aligned, padded
#define DM    64               // px per block (deform + conv), M-tile

#define N_DW  (OC * K_TOT)     // deform weight elements (589824)
#define N_OW  (32 * K_TOT)     // padded offset weight elements (73728)
#define N_CVT (2 * N_DW + 2 * N_OW)          // 1327104
#define CVT_BLOCKS (N_CVT / 4 / 512)         // 648 (512-thread blocks)
#define XT_K_ELEMS ((size_t)16 * 256 * 256)      // 1048576
#define XT_S_ELEMS ((size_t)16 * 1024 * 256)     // 4194304

typedef short  bf16x8 __attribute__((ext_vector_type(8)));
typedef float  f32x4  __attribute__((ext_vector_type(4)));
typedef unsigned short ushort_t;

__device__ __forceinline__ ushort_t f2bf(float f) {
    unsigned u = __builtin_bit_cast(unsigned, f);
    u += 0x7fffu + ((u >> 16) & 1u);          // RNE
    return (ushort_t)(u >> 16);
}
__device__ __forceinline__ float bf2f(short s) {
    return __builtin_bit_cast(float, ((unsigned)(unsigned short)s) << 16);
}

// ---------------------------------------------------------------------------
// prep kernel: (a) weight fp32->bf16 cvt with tap-major K permutation
//   dst[oc][cc][tap][cl] = src[oc][cc*32+cl][tap]   (4 elems/thread)
// (b) input transpose NCHW fp32 -> HWC bf16.
// Round-10: 512 threads/block. The transpose branch was the only untouched
// kernel piece across 9 rounds and ran at 5 waves/CU (320 blocks x 4 waves)
// with 16 latency-exposed load->cvt->LDS iterations over 55 MB — the prime
// candidate for the persistent ~110 us non-deform residual. 8 waves/block
// doubles TLP (10 waves/CU) and halves per-thread serial work; addressing
// re-derived, same LDS tile and bank behavior. Cvt branch: same 4 elems per
// thread, grid scales 1296 -> 648.
// Also zeroes the 256-elem ZERO ROW appended after xt_s (conv OOB taps).
// blockIdx.x < CVT_BLOCKS -> cvt; else transpose (320 blocks).
// ---------------------------------------------------------------------------
__global__ __launch_bounds__(512) void prep_k(
    const float* __restrict__ tdw, const float* __restrict__ sdw,
    const float* __restrict__ tow, const float* __restrict__ sow,
    const float* __restrict__ kin, const float* __restrict__ sin_,
    ushort_t* __restrict__ wk_d, ushort_t* __restrict__ ws_d,
    ushort_t* __restrict__ wk_o, ushort_t* __restrict__ ws_o,
    ushort_t* __restrict__ xt_k, ushort_t* __restrict__ xt_s)
{
    __shared__ ushort_t tile[64][264];    // transpose staging

    if (blockIdx.x == 0 && threadIdx.x < 64) {   // zero row for conv OOB taps
        ushort4 z = {0, 0, 0, 0};
        *(ushort4*)&xt_s[XT_S_ELEMS + (size_t)threadIdx.x * 4] = z;
    }

    if (blockIdx.x < CVT_BLOCKS) {
        const int i = (blockIdx.x * 512 + threadIdx.x) * 4;
        const float* src; ushort_t* dst; int j; bool offw = false;
        if (i < N_DW)                    { src = tdw; dst = wk_d; j = i; }
        else if (i < 2 * N_DW)           { src = sdw; dst = ws_d; j = i - N_DW; }
        else if (i < 2 * N_DW + N_OW)    { src = tow; dst = wk_o; j = i - 2 * N_DW; offw = true; }
        else                             { src = sow; dst = ws_o; j = i - 2 * N_DW - N_OW; offw = true; }
        const int oc = j / K_TOT;
        const int k  = j - oc * K_TOT;
        const int cc = k / KCH;
        const int r  = k - cc * KCH;     // r%4==0, so cl..cl+3 share one tap
        const int tap = r >> 5;
        const int cl  = r & 31;
        ushort4 o4 = {0, 0, 0, 0};
        if (!offw || oc < 18) {
            const float* sp = &src[((size_t)oc * CIN + cc * 32 + cl) * 9 + tap];
            o4.x = f2bf(sp[0]); o4.y = f2bf(sp[9]); o4.z = f2bf(sp[18]); o4.w = f2bf(sp[27]);
        }
        *(ushort4*)&dst[j] = o4;
        return;
    }

    // ---- transpose branch (512 thr = 8 waves) -----------------------------
    const int bx2 = blockIdx.x - CVT_BLOCKS;     // 0..319
    int H, W, b, px0; const float* x; ushort_t* xt;
    if (bx2 < 64) {                       // kernel: 16 b * 4 tiles
        H = 16; W = 16; x = kin; xt = xt_k;
        b = bx2 >> 2; px0 = (bx2 & 3) * 64;
    } else {                              // search: 16 b * 16 tiles
        int t2 = bx2 - 64;
        H = 32; W = 32; x = sin_; xt = xt_s;
        b = t2 >> 4; px0 = (t2 & 15) * 64;
    }
    const int HW = H * W;
    const int t = threadIdx.x, lane = t & 63, wv = t >> 6;   // wv: 0..7
    const float* xb = x + (size_t)b * CIN * HW;

    // loop1: each wave owns 32 channels (wv*32 + it*4 + lane>>4), 8 iters
    for (int it = 0; it < 8; ++it) {
        const int ch = wv * 32 + it * 4 + (lane >> 4);
        const int pq = (lane & 15) * 4;
        float4 v = *(const float4*)&xb[(size_t)ch * HW + px0 + pq];
        tile[pq + 0][ch] = f2bf(v.x);
        tile[pq + 1][ch] = f2bf(v.y);
        tile[pq + 2][ch] = f2bf(v.z);
        tile[pq + 3][ch] = f2bf(v.w);
    }
    __syncthreads();
    // loop2: px = it*16 + wv*2 + (lane>>5) covers 0..63 once each, 4 iters
    for (int it = 0; it < 4; ++it) {
        const int px = it * 16 + wv * 2 + (lane >> 5);
        const int cg = (lane & 31) * 8;
        bf16x8 v = *(const bf16x8*)&tile[px][cg];
        *(bf16x8*)&xt[((size_t)b * HW + px0 + px) * 256 + cg] = v;
    }
}

// ---------------------------------------------------------------------------
// Offset conv as bf16 MFMA GEMM from HWC. M=64 px/block, N=32(18), K=2304.
// (byte-identical to round 9): 320 blocks x 512 thr = 8 waves, wave = ONE
// K-chunk (kh = wv); A-issues at the r3 minimum (nt-inside), unconditional
// A-loads via branchless zero-row offset, 63 KB LDS K-reduce, XCD swizzle.
// ---------------------------------------------------------------------------
__global__ __launch_bounds__(512, 2) void conv_gemm_k(
    const ushort_t* __restrict__ xt_k, const ushort_t* __restrict__ kwgt,
    const float* __restrict__ kbias, float* __restrict__ kout,
    const ushort_t* __restrict__ xt_s, const ushort_t* __restrict__ swgt,
    const float* __restrict__ sbias, float* __restrict__ sout)
{
    __shared__ float sred[7][64][36];     // 63 KB: [kh-1][lane][(mt*2+nt)*4]

    int H, W, sh, b, px0; int zrel;
    const ushort_t* xt; const ushort_t* wgt; const float* bias; float* out;
    if (blockIdx.x < 64) {                // kernel: 16 b * 4 tiles
        const int xcd = blockIdx.x & 7, i = blockIdx.x >> 3;   // i: 0..7
        H = 16; W = 16; sh = 4; xt = xt_k; wgt = kwgt; bias = kbias; out = kout;
        b = xcd + 8 * (i & 1); px0 = (i >> 1) * 64;
        zrel = (int)(XT_K_ELEMS + XT_S_ELEMS - (size_t)b * 256 * 256);
    } else {                              // search: 16 b * 16 tiles
        const int t2 = blockIdx.x - 64;                        // 0..255
        const int xcd = t2 & 7, i = t2 >> 3;                   // i: 0..31
        H = 32; W = 32; sh = 5; xt = xt_s; wgt = swgt; bias = sbias; out = sout;
        b = xcd + 8 * (i & 1); px0 = (i >> 1) * 64;
        zrel = (int)(XT_S_ELEMS - (size_t)b * 1024 * 256);
    }
    const int HW = H * W;
    const int t = threadIdx.x, lane = t & 63, kh = t >> 6;     // kh = chunk
    const int l15 = lane & 15;
    const int cg8 = (lane >> 4) * 8;
    const ushort_t* xtb = xt + (size_t)b * HW * 256;

    // per-mt pixel coords (lane-varying)
    int h[4], wc[4];
#pragma unroll
    for (int mt = 0; mt < 4; ++mt) {
        const int px = px0 + mt * 16 + l15;
        h[mt]  = px >> sh;
        wc[mt] = px & (W - 1);
    }
    const ushort_t* wrow0 = wgt + (size_t)(l15)      * K_TOT + cg8;
    const ushort_t* wrow1 = wgt + (size_t)(16 + l15) * K_TOT + cg8;
    const int cb = kh * 32 + cg8;
    const size_t kg0 = (size_t)kh * KCH;

    f32x4 acc[4][2] = {};
#pragma unroll
    for (int ks = 0; ks < 9; ++ks) {
        const bf16x8 b0 = *(const bf16x8*)&wrow0[kg0 + (size_t)ks * 32];
        const bf16x8 b1 = *(const bf16x8*)&wrow1[kg0 + (size_t)ks * 32];
        const int dy = ks / 3 - 1, dx = ks % 3 - 1;
        bf16x8 a[4];
#pragma unroll
        for (int mt = 0; mt < 4; ++mt) {
            const int y  = h[mt] + dy;
            const int xx = wc[mt] + dx;
            const bool ok = ((unsigned)y < (unsigned)H) && ((unsigned)xx < (unsigned)W);
            const int off = ok ? (((y << sh) + xx) * 256 + cb) : (zrel + cb);
            a[mt] = *(const bf16x8*)&xtb[off];      // unconditional
        }
#pragma unroll
        for (int mt = 0; mt < 4; ++mt) {
            acc[mt][0] = __builtin_amdgcn_mfma_f32_16x16x32_bf16(a[mt], b0, acc[mt][0], 0, 0, 0);
            acc[mt][1] = __builtin_amdgcn_mfma_f32_16x16x32_bf16(a[mt], b1, acc[mt][1], 0, 0, 0);
        }
    }

    if (kh > 0) {
#pragma unroll
        for (int mt = 0; mt < 4; ++mt)
#pragma unroll
            for (int nt = 0; nt < 2; ++nt)
                *(float4*)&sred[kh - 1][lane][(mt * 2 + nt) * 4] = *(float4*)&acc[mt][nt];
    }
    __syncthreads();
    if (kh == 0) {
        const int prow = (lane >> 4) * 4;
#pragma unroll
        for (int nt = 0; nt < 2; ++nt) {
            const int oc = nt * 16 + l15;
            if (oc < 18) {
                const float bs = bias[oc];
#pragma unroll
                for (int mt = 0; mt < 4; ++mt) {
                    float4 r = *(float4*)&acc[mt][nt];
#pragma unroll
                    for (int q = 0; q < 7; ++q) {
                        const float4 o = *(const float4*)&sred[q][lane][(mt * 2 + nt) * 4];
                        r.x += o.x; r.y += o.y; r.z += o.z; r.w += o.w;
                    }
                    r.x += bs; r.y += bs; r.z += bs; r.w += bs;
                    *(float4*)(out + ((size_t)b * 18 + oc) * HW + px0 + mt * 16 + prow) = r;
                }
            }
        }
    }
}

// ---------------------------------------------------------------------------
// Deformable conv, bf16 MFMA GEMM from HWC. M=64, N=256, K=2304 tap-major.
// 320 blocks x 512 thr (8 waves); wave = oc column [wv*32,+32), mt-loop x4.
// EXACT round-5 structure (best measured: 96.2-97.7 us across 4 runs, VGPR
// 60, no spill): depth-2 gather pipeline (cA/cB), 2-deep rolling B buffer,
// XCD-bijective swizzle, raw lgkm-only barriers, setprio around MFMA.
// ---------------------------------------------------------------------------
__device__ __forceinline__ void dcn_load4(
    bf16x8* c, const ushort_t* __restrict__ xtb, int4 id, int cb)
{
    c[0] = *(const bf16x8*)&xtb[(size_t)id.x * 256 + cb];
    c[1] = *(const bf16x8*)&xtb[(size_t)id.y * 256 + cb];
    c[2] = *(const bf16x8*)&xtb[(size_t)id.z * 256 + cb];
    c[3] = *(const bf16x8*)&xtb[(size_t)id.w * 256 + cb];
}
__device__ __forceinline__ void dcn_proc2(
    ushort_t* swb, int so, const bf16x8* c, float4 wt)
{
    bf16x8 r;
#pragma unroll
    for (int j = 0; j < 8; ++j) {
        const float v = wt.x * bf2f(c[0][j]) + wt.y * bf2f(c[1][j])
                      + wt.z * bf2f(c[2][j]) + wt.w * bf2f(c[3][j]);
        r[j] = (short)f2bf(v);
    }
    *(bf16x8*)&swb[so] = r;
}

__global__ __launch_bounds__(512, 4) void deform_gemm_k(
    const ushort_t* __restrict__ xt_k, const float* __restrict__ koffs,
    const ushort_t* __restrict__ kwgt, float* __restrict__ kout,
    const ushort_t* __restrict__ xt_s, const float* __restrict__ soffs,
    const ushort_t* __restrict__ swgt_, float* __restrict__ sout)
{
    __shared__ __align__(16) ushort_t smp[DM][SSTR];    // 37.9 KB (single buf)
    __shared__ __align__(16) int      sidx[DM][9][4];   // 9.2 KB
    __shared__ __align__(16) float    swt [DM][9][4];   // 9.2 KB

    int H, W, b, px0;
    const ushort_t* xt; const float* offs; const ushort_t* wgt; float* out;
    // XCD-aware bijective swizzle: xcd = bx&7 (HW round-robin), batch = xcd
    // + 8*(i&1) so each XCD serves batches {x, x+8} only.
    if (blockIdx.x < 64) {                // kernel: 16 b * 4 tiles
        const int xcd = blockIdx.x & 7, i = blockIdx.x >> 3;   // i: 0..7
        H = 16; W = 16; xt = xt_k; offs = koffs; wgt = kwgt; out = kout;
        b = xcd + 8 * (i & 1); px0 = (i >> 1) * 64;
    } else {                              // search: 16 b * 16 tiles
        const int t2 = blockIdx.x - 64;                        // 0..255
        const int xcd = t2 & 7, i = t2 >> 3;                   // i: 0..31
        H = 32; W = 32; xt = xt_s; offs = soffs; wgt = swgt_; out = sout;
        b = xcd + 8 * (i & 1); px0 = (i >> 1) * 64;
    }
    const int HW = H * W;
    const int t = threadIdx.x, lane = t & 63, wv = t >> 6;

    // ---- phase 0: bilinear params, 576 (px,tap) units over 512 threads ----
#pragma unroll
    for (int u = 0; u < 2; ++u) {
        const int s = t + u * 512;
        if (s < DM * 9) {
            const int p = s / 9, k = s - 9 * p;
            const int pix = px0 + p;
            const int h  = pix / W;
            const int wc = pix - h * W;
            const float* ob = offs + (size_t)b * 18 * HW;
            const float dy = ob[(2 * k    ) * HW + pix];
            const float dx = ob[(2 * k + 1) * HW + pix];
            const float sy = (float)(h  + k / 3 - 1) + dy;
            const float sx = (float)(wc + k % 3 - 1) + dx;
            const float y0f = floorf(sy), x0f = floorf(sx);
            const float ly = sy - y0f, lx = sx - x0f;
            const int y0 = (int)y0f, x0 = (int)x0f;
#pragma unroll
            for (int j = 0; j < 4; ++j) {
                const int yy = y0 + (j >> 1);
                const int xx = x0 + (j & 1);
                const bool ok = ((unsigned)yy < (unsigned)H) && ((unsigned)xx < (unsigned)W);
                sidx[p][k][j] = min(max(yy, 0), H - 1) * W + min(max(xx, 0), W - 1);
                const float wj = ((j >> 1) ? ly : 1.f - ly) * ((j & 1) ? lx : 1.f - lx);
                swt[p][k][j] = ok ? wj : 0.f;
            }
        }
    }
    __syncthreads();

    const ushort_t* xtb = xt + (size_t)b * HW * 256;
    const int l15 = lane & 15;
    const int cg8 = (lane >> 4) * 8;
    const int ocb = wv * 32;
    const bool live4 = (t < 256);         // 2304 - 4*512 = 256 fifth-units

    // gather-unit geometry: unit q handles s = t + q*512;
    // g = s>>2 = g0 + q*128 (param index px*9+tap), cg = t&3 (const).
    const int g0  = t >> 2;
    const int cgE = (t & 3) * 8;          // element offset within 32-ch chunk
    int uso[5];                           // smp write offsets (elems)
#pragma unroll
    for (int q = 0; q < 5; ++q) {
        const int g  = g0 + q * 128;
        const int px = g / 9, tap = g - 9 * px;
        uso[q] = px * SSTR + tap * 32 + (t & 3) * 8;
    }

    const ushort_t* wrow0 = wgt + (size_t)(ocb      + l15) * K_TOT + cg8;
    const ushort_t* wrow1 = wgt + (size_t)(ocb + 16 + l15) * K_TOT + cg8;
    ushort_t* smpb = &smp[0][0];
    const int4*   sidxF = (const int4*)  &sidx[0][0][0];
    const float4* swtF  = (const float4*)&swt [0][0][0];

    f32x4 acc[4][2] = {};

    for (int cc = 0; cc < NCHK; ++cc) {
        const int cb = cc * 32 + cgE;
        const size_t kg0 = (size_t)cc * KCH;

        // ---- gather phase: depth-2 rolling pipeline (cA/cB slots) ---------
        bf16x8 cA[4], cB[4];
        float4 wA, wB;
        bf16x8 bq[2][2];
        { const int4 id = sidxF[g0];       wA = swtF[g0];       dcn_load4(cA, xtb, id, cb); }
        { const int4 id = sidxF[g0 + 128]; wB = swtF[g0 + 128]; dcn_load4(cB, xtb, id, cb); }
        // B ks0 group: pre-barrier issue, in flight across the barrier
        bq[0][0] = *(const bf16x8*)&wrow0[kg0];
        bq[0][1] = *(const bf16x8*)&wrow1[kg0];

        dcn_proc2(smpb, uso[0], cA, wA);
        { const int4 id = sidxF[g0 + 256]; wA = swtF[g0 + 256]; dcn_load4(cA, xtb, id, cb); }
        dcn_proc2(smpb, uso[1], cB, wB);
        { const int4 id = sidxF[g0 + 384]; wB = swtF[g0 + 384]; dcn_load4(cB, xtb, id, cb); }
        dcn_proc2(smpb, uso[2], cA, wA);
        if (live4) { const int4 id = sidxF[g0 + 512]; wA = swtF[g0 + 512]; dcn_load4(cA, xtb, id, cb); }
        dcn_proc2(smpb, uso[3], cB, wB);
        if (live4) dcn_proc2(smpb, uso[4], cA, wA);

        // ---- barrier A: smp writes visible (lgkm only, vmem in flight) ----
        asm volatile("s_waitcnt lgkmcnt(0)" ::: "memory");
        __builtin_amdgcn_sched_barrier(0);
        __builtin_amdgcn_s_barrier();
        __builtin_amdgcn_sched_barrier(0);

        // ---- MFMA phase: rolling 2-deep B register buffer -----------------
        __builtin_amdgcn_s_setprio(1);
#pragma unroll
        for (int ks = 0; ks < 9; ++ks) {
            if (ks < 8) {
                bq[(ks + 1) & 1][0] = *(const bf16x8*)&wrow0[kg0 + (size_t)(ks + 1) * 32];
                bq[(ks + 1) & 1][1] = *(const bf16x8*)&wrow1[kg0 + (size_t)(ks + 1) * 32];
            }
            bf16x8 a[4];
#pragma unroll
            for (int mt = 0; mt < 4; ++mt)
                a[mt] = *(const bf16x8*)&smp[mt * 16 + l15][ks * 32 + cg8];
#pragma unroll
            for (int mt = 0; mt < 4; ++mt) {
                acc[mt][0] = __builtin_amdgcn_mfma_f32_16x16x32_bf16(a[mt], bq[ks & 1][0], acc[mt][0], 0, 0, 0);
                acc[mt][1] = __builtin_amdgcn_mfma_f32_16x16x32_bf16(a[mt], bq[ks & 1][1], acc[mt][1], 0, 0, 0);
            }
        }
        __builtin_amdgcn_s_setprio(0);

        // ---- barrier B: all smp reads consumed before next chunk's writes -
        if (cc < NCHK - 1) {
            __builtin_amdgcn_sched_barrier(0);
            __builtin_amdgcn_s_barrier();
            __builtin_amdgcn_sched_barrier(0);
        }
    }

    // ---- epilogue ---------------------------------------------------------
    const int prow = (lane >> 4) * 4;
#pragma unroll
    for (int mt = 0; mt < 4; ++mt) {
#pragma unroll
        for (int nt = 0; nt < 2; ++nt) {
            const int oc = ocb + nt * 16 + l15;
            float* op = out + ((size_t)b * OC + oc) * HW + px0 + mt * 16 + prow;
            *(float4*)op = *(float4*)&acc[mt][nt];
        }
    }
}

// ---------------------------------------------------------------------------
// Launcher. Inputs: kernel, search, Toffset_w, Toffset_b, Tdeform_w,
//                   Soffset_w, Soffset_b, Sdeform_w
// Outputs: kernel_out[16,256,16,16], search_out[16,256,32,32],
//          kernel_offset[16,18,16,16], search_offset[16,18,32,32]
// d_ws: 13.15 MB (bf16 weights 2.66 MB + HWC inputs 10.49 MB + 512 B zero
// row appended after xt_s for conv's OOB taps).
// ---------------------------------------------------------------------------
extern "C" void kernel_launch(void* const* d_in, const int* in_sizes, int n_in,
                              void* d_out, int out_size, void* d_ws, size_t ws_size,
                              hipStream_t stream) {
    const float* kin = (const float*)d_in[0];
    const float* sin_ = (const float*)d_in[1];
    const float* tow = (const float*)d_in[2];
    const float* tob = (const float*)d_in[3];
    const float* tdw = (const float*)d_in[4];
    const float* sow = (const float*)d_in[5];
    const float* sob = (const float*)d_in[6];
    const float* sdw = (const float*)d_in[7];

    float* out = (float*)d_out;
    float* out_k  = out;                                      // 16*256*16*16
    float* out_s  = out_k + (size_t)16 * 256 * 16 * 16;       // 16*256*32*32
    float* out_ko = out_s + (size_t)16 * 256 * 32 * 32;       // 16*18*16*16
    float* out_so = out_ko + (size_t)16 * 18 * 16 * 16;       // 16*18*32*32

    ushort_t* wk_d = (ushort_t*)d_ws;                 // [256][2304] tap-major
    ushort_t* ws_d = wk_d + N_DW;
    ushort_t* wk_o = ws_d + N_DW;                     // [32][2304] tap-major
    ushort_t* ws_o = wk_o + N_OW;
    ushort_t* xt_k = ws_o + N_OW;                     // [16][256][256] HWC bf16
    ushort_t* xt_s = xt_k + XT_K_ELEMS;               // [16][1024][256]
    // zero row (256 elems) lives at xt_s + XT_S_ELEMS; prep_k writes it.

    prep_k<<<dim3(CVT_BLOCKS + 320), 512, 0, stream>>>(
        tdw, sdw, tow, sow, kin, sin_,
        wk_d, ws_d, wk_o, ws_o, xt_k, xt_s);

    conv_gemm_k<<<dim3(320), 512, 0, stream>>>(
        xt_k, wk_o, tob, out_ko, xt_s, ws_o, sob, out_so);

    deform_gemm_k<<<dim3(320), 512, 0, stream>>>(
        xt_k, out_ko, wk_d, out_k, xt_s, out_so, ws_d, out_s);
}

// Round 11
// 201.079 us; speedup vs baseline: 1.2214x; 1.0227x over previous
//
#include <hip/hip_runtime.h>

#define CIN   256
#define OC    256
#define K_TOT 2304             // 256*9
#define CCH   32               // channels per K-chunk
#define NCHK  8                // K chunks
#define KCH   288              // k-values per chunk (tap-major: k = tap*32 + c)
#define SSTR  296              // LDS row stride (bf16 elems), 16B-aligned, padded
#define DM    64               // px per block, M-tile

#define N_DW  (OC * K_TOT)     // deform weight elements (589824)
#define N_OW  (32 * K_TOT)     // padded offset weight elements (73728)
#define N_CVT (2 * N_DW + 2 * N_OW)          // 1327104
#define CVT_BLOCKS (N_CVT / 4 / 512)         // 648 (512-thread blocks)
#define XT_K_ELEMS ((size_t)16 * 256 * 256)      // 1048576
#define XT_S_ELEMS ((size_t)16 * 1024 * 256)     // 4194304

typedef short  bf16x8 __attribute__((ext_vector_type(8)));
typedef float  f32x4  __attribute__((ext_vector_type(4)));
typedef unsigned short ushort_t;

__device__ __forceinline__ ushort_t f2bf(float f) {
    unsigned u = __builtin_bit_cast(unsigned, f);
    u += 0x7fffu + ((u >> 16) & 1u);          // RNE
    return (ushort_t)(u >> 16);
}
__device__ __forceinline__ float bf2f(short s) {
    return __builtin_bit_cast(float, ((unsigned)(unsigned short)s) << 16);
}

// ---------------------------------------------------------------------------
// prep kernel (r10 structure, verified): (a) weight fp32->bf16 cvt with
// tap-major K permutation; (b) input transpose NCHW fp32 -> HWC bf16, 512
// threads (8 waves). Also zeroes the 256-elem ZERO ROW after xt_s (OOB taps).
// ---------------------------------------------------------------------------
__global__ __launch_bounds__(512) void prep_k(
    const float* __restrict__ tdw, const float* __restrict__ sdw,
    const float* __restrict__ tow, const float* __restrict__ sow,
    const float* __restrict__ kin, const float* __restrict__ sin_,
    ushort_t* __restrict__ wk_d, ushort_t* __restrict__ ws_d,
    ushort_t* __restrict__ wk_o, ushort_t* __restrict__ ws_o,
    ushort_t* __restrict__ xt_k, ushort_t* __restrict__ xt_s)
{
    __shared__ ushort_t tile[64][264];    // transpose staging

    if (blockIdx.x == 0 && threadIdx.x < 64) {   // zero row for OOB taps
        ushort4 z = {0, 0, 0, 0};
        *(ushort4*)&xt_s[XT_S_ELEMS + (size_t)threadIdx.x * 4] = z;
    }

    if (blockIdx.x < CVT_BLOCKS) {
        const int i = (blockIdx.x * 512 + threadIdx.x) * 4;
        const float* src; ushort_t* dst; int j; bool offw = false;
        if (i < N_DW)                    { src = tdw; dst = wk_d; j = i; }
        else if (i < 2 * N_DW)           { src = sdw; dst = ws_d; j = i - N_DW; }
        else if (i < 2 * N_DW + N_OW)    { src = tow; dst = wk_o; j = i - 2 * N_DW; offw = true; }
        else                             { src = sow; dst = ws_o; j = i - 2 * N_DW - N_OW; offw = true; }
        const int oc = j / K_TOT;
        const int k  = j - oc * K_TOT;
        const int cc = k / KCH;
        const int r  = k - cc * KCH;     // r%4==0, so cl..cl+3 share one tap
        const int tap = r >> 5;
        const int cl  = r & 31;
        ushort4 o4 = {0, 0, 0, 0};
        if (!offw || oc < 18) {
            const float* sp = &src[((size_t)oc * CIN + cc * 32 + cl) * 9 + tap];
            o4.x = f2bf(sp[0]); o4.y = f2bf(sp[9]); o4.z = f2bf(sp[18]); o4.w = f2bf(sp[27]);
        }
        *(ushort4*)&dst[j] = o4;
        return;
    }

    // ---- transpose branch (512 thr = 8 waves) -----------------------------
    const int bx2 = blockIdx.x - CVT_BLOCKS;     // 0..319
    int H, W, b, px0; const float* x; ushort_t* xt;
    if (bx2 < 64) {                       // kernel: 16 b * 4 tiles
        H = 16; W = 16; x = kin; xt = xt_k;
        b = bx2 >> 2; px0 = (bx2 & 3) * 64;
    } else {                              // search: 16 b * 16 tiles
        int t2 = bx2 - 64;
        H = 32; W = 32; x = sin_; xt = xt_s;
        b = t2 >> 4; px0 = (t2 & 15) * 64;
    }
    const int HW = H * W;
    const int t = threadIdx.x, lane = t & 63, wv = t >> 6;   // wv: 0..7
    const float* xb = x + (size_t)b * CIN * HW;

    for (int it = 0; it < 8; ++it) {
        const int ch = wv * 32 + it * 4 + (lane >> 4);
        const int pq = (lane & 15) * 4;
        float4 v = *(const float4*)&xb[(size_t)ch * HW + px0 + pq];
        tile[pq + 0][ch] = f2bf(v.x);
        tile[pq + 1][ch] = f2bf(v.y);
        tile[pq + 2][ch] = f2bf(v.z);
        tile[pq + 3][ch] = f2bf(v.w);
    }
    __syncthreads();
    for (int it = 0; it < 4; ++it) {
        const int px = it * 16 + wv * 2 + (lane >> 5);
        const int cg = (lane & 31) * 8;
        bf16x8 v = *(const bf16x8*)&tile[px][cg];
        *(bf16x8*)&xt[((size_t)b * HW + px0 + px) * 256 + cg] = v;
    }
}

// ---------------------------------------------------------------------------
// FUSED offset-conv + deformable-conv kernel. 320 blocks x 512 thr, same
// (b, px0) tile mapping + XCD-bijective swizzle as rounds 5-10.
//
// Phase A: offset conv for THIS tile (r9 structure: wave = one K-chunk,
//   kh = wv; unconditional A-loads via zero-row offset; 63 KB sred K-reduce;
//   kh==0 wave adds bias, writes offsets to GLOBAL (problem output) and to a
//   4.6 KB LDS buffer offsL for phase B).
// Phase B: bilinear params from offsL (no global offset round-trip).
// Phase C: deform GEMM, EXACT round-5 loop (best measured 96.2-97.7 us):
//   depth-2 gather pipeline, 2-deep rolling B buffer, raw lgkm-only
//   barriers, setprio around MFMA.
//
// LDS: sred (63 KB) UNIONS with smp+sidx+swt (56.3 KB) — phase-disjoint,
// barrier-separated. + offsL 4.6 KB => 67.5 KB => 2 blocks/CU.
// Why fuse: removes the conv kernel launch AND the device-wide drain between
// conv and deform (deform previously waited for the LAST conv block), and
// makes conv's true cost visible in the fused dispatch duration (minus 97).
// ---------------------------------------------------------------------------
__device__ __forceinline__ void dcn_load4(
    bf16x8* c, const ushort_t* __restrict__ xtb, int4 id, int cb)
{
    c[0] = *(const bf16x8*)&xtb[(size_t)id.x * 256 + cb];
    c[1] = *(const bf16x8*)&xtb[(size_t)id.y * 256 + cb];
    c[2] = *(const bf16x8*)&xtb[(size_t)id.z * 256 + cb];
    c[3] = *(const bf16x8*)&xtb[(size_t)id.w * 256 + cb];
}
__device__ __forceinline__ void dcn_proc2(
    ushort_t* swb, int so, const bf16x8* c, float4 wt)
{
    bf16x8 r;
#pragma unroll
    for (int j = 0; j < 8; ++j) {
        const float v = wt.x * bf2f(c[0][j]) + wt.y * bf2f(c[1][j])
                      + wt.z * bf2f(c[2][j]) + wt.w * bf2f(c[3][j]);
        r[j] = (short)f2bf(v);
    }
    *(bf16x8*)&swb[so] = r;
}

__global__ __launch_bounds__(512, 4) void deform_gemm_k(
    const ushort_t* __restrict__ xt_k,
    const ushort_t* __restrict__ kwo, const float* __restrict__ kbias,
    float* __restrict__ koff, const ushort_t* __restrict__ kwd,
    float* __restrict__ kout,
    const ushort_t* __restrict__ xt_s,
    const ushort_t* __restrict__ swo, const float* __restrict__ sbias,
    float* __restrict__ soff, const ushort_t* __restrict__ swd,
    float* __restrict__ sout)
{
    // union region: sred[7][64][36] f32 (64512 B) overlays
    //   smp[64][SSTR] u16 (37888 B) + sidx[64][9][4] i32 (9216 B, @37888)
    //   + swt[64][9][4] f32 (9216 B, @47104)
    __shared__ __align__(16) char  uni[64512];
    __shared__ __align__(16) float offsL[18][64];       // 4608 B

    float    (*sred)[64][36] = (float(*)[64][36])uni;
    ushort_t (*smp)[SSTR]    = (ushort_t(*)[SSTR])uni;
    int      (*sidx)[9][4]   = (int(*)[9][4])(uni + 37888);
    float    (*swt)[9][4]    = (float(*)[9][4])(uni + 47104);

    int H, W, sh, b, px0; int zrel;
    const ushort_t *xt, *wgo, *wgd; const float* bias; float *ooff, *out;
    if (blockIdx.x < 64) {                // kernel: 16 b * 4 tiles
        const int xcd = blockIdx.x & 7, i = blockIdx.x >> 3;   // i: 0..7
        H = 16; W = 16; sh = 4; xt = xt_k; wgo = kwo; bias = kbias;
        ooff = koff; wgd = kwd; out = kout;
        b = xcd + 8 * (i & 1); px0 = (i >> 1) * 64;
        zrel = (int)(XT_K_ELEMS + XT_S_ELEMS - (size_t)b * 256 * 256);
    } else {                              // search: 16 b * 16 tiles
        const int t2 = blockIdx.x - 64;                        // 0..255
        const int xcd = t2 & 7, i = t2 >> 3;                   // i: 0..31
        H = 32; W = 32; sh = 5; xt = xt_s; wgo = swo; bias = sbias;
        ooff = soff; wgd = swd; out = sout;
        b = xcd + 8 * (i & 1); px0 = (i >> 1) * 64;
        zrel = (int)(XT_S_ELEMS - (size_t)b * 1024 * 256);
    }
    const int HW = H * W;
    const int t = threadIdx.x, lane = t & 63, wv = t >> 6;
    const int l15 = lane & 15;
    const int cg8 = (lane >> 4) * 8;
    const ushort_t* xtb = xt + (size_t)b * HW * 256;

    // ===================== phase A: offset conv ============================
    {
        const int kh = wv;                // wave = one K-chunk
        int h[4], wc[4];
#pragma unroll
        for (int mt = 0; mt < 4; ++mt) {
            const int px = px0 + mt * 16 + l15;
            h[mt]  = px >> sh;
            wc[mt] = px & (W - 1);
        }
        const ushort_t* wrow0 = wgo + (size_t)(l15)      * K_TOT + cg8;
        const ushort_t* wrow1 = wgo + (size_t)(16 + l15) * K_TOT + cg8;
        const int cb = kh * 32 + cg8;
        const size_t kg0 = (size_t)kh * KCH;

        f32x4 acc[4][2] = {};
#pragma unroll
        for (int ks = 0; ks < 9; ++ks) {
            const bf16x8 b0 = *(const bf16x8*)&wrow0[kg0 + (size_t)ks * 32];
            const bf16x8 b1 = *(const bf16x8*)&wrow1[kg0 + (size_t)ks * 32];
            const int dy = ks / 3 - 1, dx = ks % 3 - 1;
            bf16x8 a[4];
#pragma unroll
            for (int mt = 0; mt < 4; ++mt) {
                const int y  = h[mt] + dy;
                const int xx = wc[mt] + dx;
                const bool ok = ((unsigned)y < (unsigned)H) && ((unsigned)xx < (unsigned)W);
                const int off = ok ? (((y << sh) + xx) * 256 + cb) : (zrel + cb);
                a[mt] = *(const bf16x8*)&xtb[off];      // unconditional
            }
#pragma unroll
            for (int mt = 0; mt < 4; ++mt) {
                acc[mt][0] = __builtin_amdgcn_mfma_f32_16x16x32_bf16(a[mt], b0, acc[mt][0], 0, 0, 0);
                acc[mt][1] = __builtin_amdgcn_mfma_f32_16x16x32_bf16(a[mt], b1, acc[mt][1], 0, 0, 0);
            }
        }

        if (kh > 0) {
#pragma unroll
            for (int mt = 0; mt < 4; ++mt)
#pragma unroll
                for (int nt = 0; nt < 2; ++nt)
                    *(float4*)&sred[kh - 1][lane][(mt * 2 + nt) * 4] = *(float4*)&acc[mt][nt];
        }
        __syncthreads();
        if (kh == 0) {
            const int prow = (lane >> 4) * 4;
#pragma unroll
            for (int nt = 0; nt < 2; ++nt) {
                const int oc = nt * 16 + l15;
                if (oc < 18) {
                    const float bs = bias[oc];
#pragma unroll
                    for (int mt = 0; mt < 4; ++mt) {
                        float4 r = *(float4*)&acc[mt][nt];
#pragma unroll
                        for (int q = 0; q < 7; ++q) {
                            const float4 o = *(const float4*)&sred[q][lane][(mt * 2 + nt) * 4];
                            r.x += o.x; r.y += o.y; r.z += o.z; r.w += o.w;
                        }
                        r.x += bs; r.y += bs; r.z += bs; r.w += bs;
                        *(float4*)(ooff + ((size_t)b * 18 + oc) * HW + px0 + mt * 16 + prow) = r;
                        *(float4*)&offsL[oc][mt * 16 + prow] = r;
                    }
                }
            }
        }
        __syncthreads();     // offsL visible; sred region now dead
    }

    // ===================== phase B: bilinear params ========================
#pragma unroll
    for (int u = 0; u < 2; ++u) {
        const int s = t + u * 512;
        if (s < DM * 9) {
            const int p = s / 9, k = s - 9 * p;
            const int pix = px0 + p;
            const int hh = pix >> sh;
            const int ww = pix & (W - 1);
            const float dy = offsL[2 * k    ][p];
            const float dx = offsL[2 * k + 1][p];
            const float sy = (float)(hh + k / 3 - 1) + dy;
            const float sx = (float)(ww + k % 3 - 1) + dx;
            const float y0f = floorf(sy), x0f = floorf(sx);
            const float ly = sy - y0f, lx = sx - x0f;
            const int y0 = (int)y0f, x0 = (int)x0f;
#pragma unroll
            for (int j = 0; j < 4; ++j) {
                const int yy = y0 + (j >> 1);
                const int xx = x0 + (j & 1);
                const bool ok = ((unsigned)yy < (unsigned)H) && ((unsigned)xx < (unsigned)W);
                sidx[p][k][j] = min(max(yy, 0), H - 1) * W + min(max(xx, 0), W - 1);
                const float wj = ((j >> 1) ? ly : 1.f - ly) * ((j & 1) ? lx : 1.f - lx);
                swt[p][k][j] = ok ? wj : 0.f;
            }
        }
    }
    __syncthreads();

    // ===================== phase C: deform GEMM (r5 loop) ==================
    const int ocb = wv * 32;
    const bool live4 = (t < 256);         // 2304 - 4*512 = 256 fifth-units

    const int g0  = t >> 2;
    const int cgE = (t & 3) * 8;
    int uso[5];
#pragma unroll
    for (int q = 0; q < 5; ++q) {
        const int g  = g0 + q * 128;
        const int px = g / 9, tap = g - 9 * px;
        uso[q] = px * SSTR + tap * 32 + (t & 3) * 8;
    }

    const ushort_t* wrow0 = wgd + (size_t)(ocb      + l15) * K_TOT + cg8;
    const ushort_t* wrow1 = wgd + (size_t)(ocb + 16 + l15) * K_TOT + cg8;
    ushort_t* smpb = &smp[0][0];
    const int4*   sidxF = (const int4*)  &sidx[0][0][0];
    const float4* swtF  = (const float4*)&swt [0][0][0];

    f32x4 acc[4][2] = {};

    for (int cc = 0; cc < NCHK; ++cc) {
        const int cb = cc * 32 + cgE;
        const size_t kg0 = (size_t)cc * KCH;

        // ---- gather phase: depth-2 rolling pipeline (cA/cB slots) ---------
        bf16x8 cA[4], cB[4];
        float4 wA, wB;
        bf16x8 bq[2][2];
        { const int4 id = sidxF[g0];       wA = swtF[g0];       dcn_load4(cA, xtb, id, cb); }
        { const int4 id = sidxF[g0 + 128]; wB = swtF[g0 + 128]; dcn_load4(cB, xtb, id, cb); }
        bq[0][0] = *(const bf16x8*)&wrow0[kg0];
        bq[0][1] = *(const bf16x8*)&wrow1[kg0];

        dcn_proc2(smpb, uso[0], cA, wA);
        { const int4 id = sidxF[g0 + 256]; wA = swtF[g0 + 256]; dcn_load4(cA, xtb, id, cb); }
        dcn_proc2(smpb, uso[1], cB, wB);
        { const int4 id = sidxF[g0 + 384]; wB = swtF[g0 + 384]; dcn_load4(cB, xtb, id, cb); }
        dcn_proc2(smpb, uso[2], cA, wA);
        if (live4) { const int4 id = sidxF[g0 + 512]; wA = swtF[g0 + 512]; dcn_load4(cA, xtb, id, cb); }
        dcn_proc2(smpb, uso[3], cB, wB);
        if (live4) dcn_proc2(smpb, uso[4], cA, wA);

        // ---- barrier A: smp writes visible (lgkm only, vmem in flight) ----
        asm volatile("s_waitcnt lgkmcnt(0)" ::: "memory");
        __builtin_amdgcn_sched_barrier(0);
        __builtin_amdgcn_s_barrier();
        __builtin_amdgcn_sched_barrier(0);

        // ---- MFMA phase: rolling 2-deep B register buffer -----------------
        __builtin_amdgcn_s_setprio(1);
#pragma unroll
        for (int ks = 0; ks < 9; ++ks) {
            if (ks < 8) {
                bq[(ks + 1) & 1][0] = *(const bf16x8*)&wrow0[kg0 + (size_t)(ks + 1) * 32];
                bq[(ks + 1) & 1][1] = *(const bf16x8*)&wrow1[kg0 + (size_t)(ks + 1) * 32];
            }
            bf16x8 a[4];
#pragma unroll
            for (int mt = 0; mt < 4; ++mt)
                a[mt] = *(const bf16x8*)&smp[mt * 16 + l15][ks * 32 + cg8];
#pragma unroll
            for (int mt = 0; mt < 4; ++mt) {
                acc[mt][0] = __builtin_amdgcn_mfma_f32_16x16x32_bf16(a[mt], bq[ks & 1][0], acc[mt][0], 0, 0, 0);
                acc[mt][1] = __builtin_amdgcn_mfma_f32_16x16x32_bf16(a[mt], bq[ks & 1][1], acc[mt][1], 0, 0, 0);
            }
        }
        __builtin_amdgcn_s_setprio(0);

        // ---- barrier B: all smp reads consumed before next chunk's writes -
        if (cc < NCHK - 1) {
            __builtin_amdgcn_sched_barrier(0);
            __builtin_amdgcn_s_barrier();
            __builtin_amdgcn_sched_barrier(0);
        }
    }

    // ---- epilogue ---------------------------------------------------------
    const int prow = (lane >> 4) * 4;
#pragma unroll
    for (int mt = 0; mt < 4; ++mt) {
#pragma unroll
        for (int nt = 0; nt < 2; ++nt) {
            const int oc = ocb + nt * 16 + l15;
            float* op = out + ((size_t)b * OC + oc) * HW + px0 + mt * 16 + prow;
            *(float4*)op = *(float4*)&acc[mt][nt];
        }
    }
}

// ---------------------------------------------------------------------------
// Launcher. Inputs: kernel, search, Toffset_w, Toffset_b, Tdeform_w,
//                   Soffset_w, Soffset_b, Sdeform_w
// Outputs: kernel_out[16,256,16,16], search_out[16,256,32,32],
//          kernel_offset[16,18,16,16], search_offset[16,18,32,32]
// d_ws: 13.15 MB (bf16 weights 2.66 MB + HWC inputs 10.49 MB + 512 B zero
// row appended after xt_s for OOB taps).
// ---------------------------------------------------------------------------
extern "C" void kernel_launch(void* const* d_in, const int* in_sizes, int n_in,
                              void* d_out, int out_size, void* d_ws, size_t ws_size,
                              hipStream_t stream) {
    const float* kin = (const float*)d_in[0];
    const float* sin_ = (const float*)d_in[1];
    const float* tow = (const float*)d_in[2];
    const float* tob = (const float*)d_in[3];
    const float* tdw = (const float*)d_in[4];
    const float* sow = (const float*)d_in[5];
    const float* sob = (const float*)d_in[6];
    const float* sdw = (const float*)d_in[7];

    float* out = (float*)d_out;
    float* out_k  = out;                                      // 16*256*16*16
    float* out_s  = out_k + (size_t)16 * 256 * 16 * 16;       // 16*256*32*32
    float* out_ko = out_s + (size_t)16 * 256 * 32 * 32;       // 16*18*16*16
    float* out_so = out_ko + (size_t)16 * 18 * 16 * 16;       // 16*18*32*32

    ushort_t* wk_d = (ushort_t*)d_ws;                 // [256][2304] tap-major
    ushort_t* ws_d = wk_d + N_DW;
    ushort_t* wk_o = ws_d + N_DW;                     // [32][2304] tap-major
    ushort_t* ws_o = wk_o + N_OW;
    ushort_t* xt_k = ws_o + N_OW;                     // [16][256][256] HWC bf16
    ushort_t* xt_s = xt_k + XT_K_ELEMS;               // [16][1024][256]
    // zero row (256 elems) lives at xt_s + XT_S_ELEMS; prep_k writes it.

    prep_k<<<dim3(CVT_BLOCKS + 320), 512, 0, stream>>>(
        tdw, sdw, tow, sow, kin, sin_,
        wk_d, ws_d, wk_o, ws_o, xt_k, xt_s);

    deform_gemm_k<<<dim3(320), 512, 0, stream>>>(
        xt_k, wk_o, tob, out_ko, wk_d, out_k,
        xt_s, ws_o, sob, out_so, ws_d, out_s);
}